// Round 1
// baseline (1195.847 us; speedup 1.0000x reference)
//
#include <hip/hip_runtime.h>
#include <hip/hip_bf16.h>
#include <cstddef>

#define NND 16384
#define NE  32
#define HD  256
#define AD  64
#define ODIM 5

__device__ __forceinline__ float sigmoidf_(float x) {
  return 1.f / (1.f + __expf(-x));
}

// ---------------------------------------------------------------------------
// K0: MT[h][k] = sum_a Wt[a,k]*Ws[a,h]   (256x256), u[h] = sum_a bt[a]*Ws[a,h]
// ---------------------------------------------------------------------------
__global__ __launch_bounds__(256) void k_mt(const float* __restrict__ Wt,
                                            const float* __restrict__ bt,
                                            const float* __restrict__ Ws,
                                            float* __restrict__ MT,
                                            float* __restrict__ u) {
  const int h = blockIdx.x;    // output row of MT
  const int k = threadIdx.x;   // col
  float acc = 0.f;
  #pragma unroll
  for (int a = 0; a < AD; ++a)
    acc += Wt[a * HD + k] * Ws[a * HD + h];
  MT[h * HD + k] = acc;
  if (k == 0) {
    float s = 0.f;
    #pragma unroll
    for (int a = 0; a < AD; ++a) s += bt[a] * Ws[a * HD + h];
    u[h] = s;
  }
}

// ---------------------------------------------------------------------------
// Generic fused fp32 GEMM:  out[m][c] = epilogue( sum_p A_p[m,:] . W_p[c,:] + bias[c] )
// A sources are N x 256 (row stride 256). W_p row stride ldw_p.
// modes: 0 = linear(+bias), 1 = relu, 2 = sigmoid(+bias),
//        3 = prev * sigmoid(+bias), 4 = hidden combine: (1-z)*relu(+bias) + z*prev
// BM=BN=128, BK=32, 256 threads, 8x8 micro-tile (4+4 split in both dims).
// ---------------------------------------------------------------------------
#define BM 128
#define BN 128
#define BKT 32
#define LDP 132

__global__ __launch_bounds__(256) void gemm_fused(
    const float* __restrict__ A0, const float* __restrict__ W0, int ldw0, int k0,
    const float* __restrict__ A1, const float* __restrict__ W1, int ldw1, int k1,
    const float* __restrict__ A2, const float* __restrict__ W2, int ldw2, int k2,
    const float* __restrict__ bias,
    const float* __restrict__ prev,
    const float* __restrict__ zbuf,
    float* __restrict__ out, int mode) {
  __shared__ float As[BKT][LDP];
  __shared__ float Wsh[BKT][LDP];
  const int tid = threadIdx.x;
  const int tx = tid & 15, ty = tid >> 4;
  const int row0 = blockIdx.y * BM, col0 = blockIdx.x * BN;

  float acc[8][8];
  #pragma unroll
  for (int i = 0; i < 8; ++i)
    #pragma unroll
    for (int j = 0; j < 8; ++j) acc[i][j] = 0.f;

  const int sr = tid >> 1;          // staging row 0..127
  const int sk = (tid & 1) * 16;    // staging k offset 0/16

  const float* Aps[3] = {A0, A1, A2};
  const float* Wps[3] = {W0, W1, W2};
  const int lws[3] = {ldw0, ldw1, ldw2};
  const int ks[3] = {k0, k1, k2};

  #pragma unroll
  for (int p = 0; p < 3; ++p) {
    const float* Ap = Aps[p];
    if (!Ap) break;
    const float* Wp = Wps[p];
    const int ldw = lws[p];
    const int nk = ks[p] / BKT;
    for (int kt = 0; kt < nk; ++kt) {
      const float* ag = Ap + (size_t)(row0 + sr) * HD + kt * BKT + sk;
      const float* wg = Wp + (size_t)(col0 + sr) * ldw + kt * BKT + sk;
      float4 a0 = ((const float4*)ag)[0];
      float4 a1 = ((const float4*)ag)[1];
      float4 a2 = ((const float4*)ag)[2];
      float4 a3 = ((const float4*)ag)[3];
      float4 w0 = ((const float4*)wg)[0];
      float4 w1 = ((const float4*)wg)[1];
      float4 w2 = ((const float4*)wg)[2];
      float4 w3 = ((const float4*)wg)[3];
      __syncthreads();
      As[sk + 0][sr] = a0.x;  As[sk + 1][sr] = a0.y;  As[sk + 2][sr] = a0.z;  As[sk + 3][sr] = a0.w;
      As[sk + 4][sr] = a1.x;  As[sk + 5][sr] = a1.y;  As[sk + 6][sr] = a1.z;  As[sk + 7][sr] = a1.w;
      As[sk + 8][sr] = a2.x;  As[sk + 9][sr] = a2.y;  As[sk + 10][sr] = a2.z; As[sk + 11][sr] = a2.w;
      As[sk + 12][sr] = a3.x; As[sk + 13][sr] = a3.y; As[sk + 14][sr] = a3.z; As[sk + 15][sr] = a3.w;
      Wsh[sk + 0][sr] = w0.x;  Wsh[sk + 1][sr] = w0.y;  Wsh[sk + 2][sr] = w0.z;  Wsh[sk + 3][sr] = w0.w;
      Wsh[sk + 4][sr] = w1.x;  Wsh[sk + 5][sr] = w1.y;  Wsh[sk + 6][sr] = w1.z;  Wsh[sk + 7][sr] = w1.w;
      Wsh[sk + 8][sr] = w2.x;  Wsh[sk + 9][sr] = w2.y;  Wsh[sk + 10][sr] = w2.z; Wsh[sk + 11][sr] = w2.w;
      Wsh[sk + 12][sr] = w3.x; Wsh[sk + 13][sr] = w3.y; Wsh[sk + 14][sr] = w3.z; Wsh[sk + 15][sr] = w3.w;
      __syncthreads();
      #pragma unroll
      for (int kk = 0; kk < BKT; ++kk) {
        float4 aA = *(const float4*)&As[kk][ty * 4];
        float4 aB = *(const float4*)&As[kk][64 + ty * 4];
        float4 wA = *(const float4*)&Wsh[kk][tx * 4];
        float4 wB = *(const float4*)&Wsh[kk][64 + tx * 4];
        float av[8] = {aA.x, aA.y, aA.z, aA.w, aB.x, aB.y, aB.z, aB.w};
        float wv[8] = {wA.x, wA.y, wA.z, wA.w, wB.x, wB.y, wB.z, wB.w};
        #pragma unroll
        for (int i = 0; i < 8; ++i)
          #pragma unroll
          for (int j = 0; j < 8; ++j) acc[i][j] += av[i] * wv[j];
      }
    }
  }

  #pragma unroll
  for (int ii = 0; ii < 8; ++ii) {
    const int m = row0 + ((ii >> 2) << 6) + ty * 4 + (ii & 3);
    #pragma unroll
    for (int jj = 0; jj < 2; ++jj) {
      const int c = col0 + (jj << 6) + tx * 4;
      float r[4];
      #pragma unroll
      for (int q = 0; q < 4; ++q) {
        float a = acc[ii][jj * 4 + q];
        if (bias) a += bias[c + q];
        if (mode == 1) {
          a = fmaxf(a, 0.f);
        } else if (mode == 2) {
          a = sigmoidf_(a);
        } else if (mode == 3) {
          a = prev[(size_t)m * HD + c + q] * sigmoidf_(a);
        } else if (mode == 4) {
          float nv = fmaxf(a, 0.f);
          float zz = zbuf[(size_t)m * HD + c + q];
          float pv = prev[(size_t)m * HD + c + q];
          a = (1.f - zz) * nv + zz * pv;
        }
        r[q] = a;
      }
      *(float4*)&out[(size_t)m * HD + c] = make_float4(r[0], r[1], r[2], r[3]);
    }
  }
}

// ---------------------------------------------------------------------------
// K2: attention, one node per block. spat slice held entirely in registers.
// Thread t's 8 coalesced float4 loads (index t+256*i) each belong to edge
// e = (t>>6)+4*i, element 4*(t&63).. — wave-uniform edge => shfl reduce.
// ---------------------------------------------------------------------------
__global__ __launch_bounds__(256) void k_attn(const float* __restrict__ spat,
                                              const float* __restrict__ v,
                                              float* __restrict__ hagg) {
  __shared__ float attn_s[NE];
  __shared__ float4 part_s[4][64];
  const int n = blockIdx.x;
  const int t = threadIdx.x;
  const int w = t >> 6, fb = t & 63;
  const float4* sp = (const float4*)(spat + (size_t)n * NE * HD);
  const float4 v4 = ((const float4*)(v + (size_t)n * HD))[fb];

  float4 sreg[8];
  float part[8];
  #pragma unroll
  for (int i = 0; i < 8; ++i) {
    sreg[i] = sp[t + 256 * i];
    part[i] = sreg[i].x * v4.x + sreg[i].y * v4.y + sreg[i].z * v4.z + sreg[i].w * v4.w;
  }
  #pragma unroll
  for (int i = 0; i < 8; ++i) {
    float p = part[i];
    #pragma unroll
    for (int m = 1; m < 64; m <<= 1) p += __shfl_xor(p, m, 64);
    if (fb == 0) attn_s[w + 4 * i] = p;
  }
  __syncthreads();
  // softmax over the 32 edges (redundant per thread), temperature = E/sqrt(A) = 4
  float mx = -1e30f;
  for (int e = 0; e < NE; ++e) mx = fmaxf(mx, attn_s[e] * 4.0f);
  float s = 0.f;
  for (int e = 0; e < NE; ++e) s += __expf(attn_s[e] * 4.0f - mx);
  const float inv = 1.f / s;
  float4 hp = make_float4(0.f, 0.f, 0.f, 0.f);
  #pragma unroll
  for (int i = 0; i < 8; ++i) {
    const float wgt = __expf(attn_s[w + 4 * i] * 4.0f - mx) * inv;
    hp.x += wgt * sreg[i].x;
    hp.y += wgt * sreg[i].y;
    hp.z += wgt * sreg[i].z;
    hp.w += wgt * sreg[i].w;
  }
  part_s[w][fb] = hp;
  __syncthreads();
  if (t < 64) {
    float4 s0 = part_s[0][t], s1 = part_s[1][t], s2 = part_s[2][t], s3 = part_s[3][t];
    float4 o = make_float4(s0.x + s1.x + s2.x + s3.x, s0.y + s1.y + s2.y + s3.y,
                           s0.z + s1.z + s2.z + s3.z, s0.w + s1.w + s2.w + s3.w);
    ((float4*)(hagg + (size_t)n * HD))[t] = o;
  }
}

// ---------------------------------------------------------------------------
// K3: x_e = relu(xy @ W_xy^T)
// ---------------------------------------------------------------------------
__global__ __launch_bounds__(256) void k_xe(const float* __restrict__ xy,
                                            const float* __restrict__ Wxy,
                                            float* __restrict__ xe) {
  const int h = threadIdx.x;
  const float w0 = Wxy[2 * h], w1 = Wxy[2 * h + 1];
  for (int n = blockIdx.x; n < NND; n += gridDim.x) {
    const float x0 = xy[2 * n], x1 = xy[2 * n + 1];
    xe[(size_t)n * HD + h] = fmaxf(x0 * w0 + x1 * w1, 0.f);
  }
}

// ---------------------------------------------------------------------------
// K8: predict = hidden @ W_pred^T + b_pred  (one wave per node)
// ---------------------------------------------------------------------------
__global__ __launch_bounds__(256) void k_pred(const float* __restrict__ hid,
                                              const float* __restrict__ Wp,
                                              const float* __restrict__ bp,
                                              float* __restrict__ out) {
  const int t = threadIdx.x;
  const int w = t >> 6, lane = t & 63;
  const int n = blockIdx.x * 4 + w;
  const float* h = hid + (size_t)n * HD;
  const float h0 = h[lane], h1 = h[lane + 64], h2 = h[lane + 128], h3 = h[lane + 192];
  #pragma unroll
  for (int oc = 0; oc < ODIM; ++oc) {
    const float* wr = Wp + oc * HD;
    float p = h0 * wr[lane] + h1 * wr[lane + 64] + h2 * wr[lane + 128] + h3 * wr[lane + 192];
    #pragma unroll
    for (int m = 1; m < 64; m <<= 1) p += __shfl_xor(p, m, 64);
    if (lane == 0) out[n * ODIM + oc] = p + bp[oc];
  }
}

// ---------------------------------------------------------------------------
extern "C" void kernel_launch(void* const* d_in, const int* in_sizes, int n_in,
                              void* d_out, int out_size, void* d_ws, size_t ws_size,
                              hipStream_t stream) {
  const float* xy   = (const float*)d_in[0];
  const float* th   = (const float*)d_in[1];
  const float* spat = (const float*)d_in[2];
  const float* prev = (const float*)d_in[3];
  const float* Wt   = (const float*)d_in[4];
  const float* bt   = (const float*)d_in[5];
  const float* Ws   = (const float*)d_in[6];
  // d_in[7] = bs: constant shift across edges -> cancels in softmax, unused
  const float* Wxy  = (const float*)d_in[8];
  const float* Whe  = (const float*)d_in[9];
  const float* Wih  = (const float*)d_in[10];
  const float* Whh  = (const float*)d_in[11];
  const float* bg   = (const float*)d_in[12];
  const float* Wp   = (const float*)d_in[13];
  const float* bp   = (const float*)d_in[14];
  float* out = (float*)d_out;

  float* ws   = (float*)d_ws;
  float* MT   = ws;                                // 256*256
  float* u    = MT + 65536;                        // 256
  float* vbuf = u + 256;                           // N*256 (aliased: z after attn)
  float* hagg = vbuf + (size_t)NND * HD;           // N*256 (aliased: rp after H_e)
  float* xe   = hagg + (size_t)NND * HD;           // N*256
  float* He   = xe + (size_t)NND * HD;             // N*256

  const dim3 gg(HD / BN, NND / BM);  // (2, 128)

  // K0: fold attention projections: MT = (Wt^T Ws)^T, u = bt @ Ws
  k_mt<<<256, 256, 0, stream>>>(Wt, bt, Ws, MT, u);
  // K1: v = th @ MT^T(rows) + u
  gemm_fused<<<gg, 256, 0, stream>>>(th, MT, HD, HD,
                                     nullptr, nullptr, 0, 0,
                                     nullptr, nullptr, 0, 0,
                                     u, nullptr, nullptr, vbuf, 0);
  // K2: attention -> Hagg
  k_attn<<<NND, 256, 0, stream>>>(spat, vbuf, hagg);
  // K3: x_e
  k_xe<<<2048, 256, 0, stream>>>(xy, Wxy, xe);
  // K4: H_e = relu([th, Hagg] @ W_he^T)
  gemm_fused<<<gg, 256, 0, stream>>>(th, Whe, 2 * HD, HD,
                                     hagg, Whe + HD, 2 * HD, HD,
                                     nullptr, nullptr, 0, 0,
                                     nullptr, nullptr, nullptr, He, 1);
  // K5: z = sigmoid(cat@Wih0^T + prev@Whh0^T + b0)   (z overwrites vbuf)
  gemm_fused<<<gg, 256, 0, stream>>>(xe, Wih, 2 * HD, HD,
                                     He, Wih + HD, 2 * HD, HD,
                                     prev, Whh, HD, HD,
                                     bg, nullptr, nullptr, vbuf, 2);
  // K6: rp = prev * sigmoid(cat@Wih1^T + prev@Whh1^T + b1)   (rp overwrites hagg)
  gemm_fused<<<gg, 256, 0, stream>>>(xe, Wih + 131072, 2 * HD, HD,
                                     He, Wih + 131072 + HD, 2 * HD, HD,
                                     prev, Whh + 65536, HD, HD,
                                     bg + HD, prev, nullptr, hagg, 3);
  // K7: n = relu(cat@Wih2^T + rp@Whh2^T + b2); hidden = (1-z)*n + z*prev
  gemm_fused<<<gg, 256, 0, stream>>>(xe, Wih + 262144, 2 * HD, HD,
                                     He, Wih + 262144 + HD, 2 * HD, HD,
                                     hagg, Whh + 131072, HD, HD,
                                     bg + 2 * HD, prev, vbuf, out + NND * ODIM, 4);
  // K8: predict
  k_pred<<<NND / 4, 256, 0, stream>>>(out + NND * ODIM, Wp, bp, out);
}

// Round 2
// 953.584 us; speedup vs baseline: 1.2541x; 1.2541x over previous
//
#include <hip/hip_runtime.h>
#include <hip/hip_bf16.h>
#include <cstddef>

#define NND 16384
#define NE  32
#define HD  256
#define AD  64
#define ODIM 5

typedef __attribute__((ext_vector_type(8))) short bf16x8;
typedef __attribute__((ext_vector_type(4))) float f32x4;

__device__ __forceinline__ float sigmoidf_(float x) {
  return 1.f / (1.f + __expf(-x));
}
__device__ __forceinline__ unsigned short f2b(float x) {
  __hip_bfloat16 b = __float2bfloat16(x);
  return *reinterpret_cast<unsigned short*>(&b);
}

// ---------------------------------------------------------------------------
// K0: MT[h][k] = sum_a Wt[a,k]*Ws[a,h]   (256x256), u[h] = sum_a bt[a]*Ws[a,h]
// ---------------------------------------------------------------------------
__global__ __launch_bounds__(256) void k_mt(const float* __restrict__ Wt,
                                            const float* __restrict__ bt,
                                            const float* __restrict__ Ws,
                                            float* __restrict__ MT,
                                            float* __restrict__ u) {
  const int h = blockIdx.x;
  const int k = threadIdx.x;
  float acc = 0.f;
  #pragma unroll
  for (int a = 0; a < AD; ++a)
    acc += Wt[a * HD + k] * Ws[a * HD + h];
  MT[h * HD + k] = acc;
  if (k == 0) {
    float s = 0.f;
    #pragma unroll
    for (int a = 0; a < AD; ++a) s += bt[a] * Ws[a * HD + h];
    u[h] = s;
  }
}

// ---------------------------------------------------------------------------
// bf16-MFMA fused GEMM: out[m][c] = epi( sum_p A_p[m,:].W_p[c,:] + bias[c] )
// A_p: N x 256 fp32 (row stride 256). W_p fp32, row stride ldw_p.
// fp32 -> bf16 conversion fused into LDS staging. fp32 accumulate (MFMA).
// BM=BN=128, BK=32, 256 thr, 4 waves in 2x2, each wave 64x64 (4x4 frags of
// 16x16x32). LDS rows padded to 40 bf16 (80B) -> <=2-way bank conflicts.
// Register double-buffer: next tile's global loads issue under current MFMAs.
// modes: 0=linear(+bias) 1=relu 2=sigmoid(+bias) 3=prev*sigmoid(+bias)
//        4=(1-z)*relu(+bias)+z*prev
// ---------------------------------------------------------------------------
#define BM 128
#define BN 128
#define BKT 32
#define LDP 40

__global__ __launch_bounds__(256) void gemm_bf16(
    const float* __restrict__ A0, const float* __restrict__ W0, int ldw0, int k0,
    const float* __restrict__ A1, const float* __restrict__ W1, int ldw1, int k1,
    const float* __restrict__ A2, const float* __restrict__ W2, int ldw2, int k2,
    const float* __restrict__ bias,
    const float* __restrict__ prev,
    const float* __restrict__ zbuf,
    float* __restrict__ out, int mode) {
  __shared__ __align__(16) unsigned short As[BM * LDP];
  __shared__ __align__(16) unsigned short Bs[BM * LDP];

  const int tid = threadIdx.x;
  const int lane = tid & 63, wid = tid >> 6;
  const int wr = wid >> 1, wc = wid & 1;
  const int fr = lane & 15, fq = lane >> 4;
  const int row0 = blockIdx.y * BM, col0 = blockIdx.x * BN;

  f32x4 acc[4][4];
  #pragma unroll
  for (int i = 0; i < 4; ++i)
    #pragma unroll
    for (int j = 0; j < 4; ++j)
      #pragma unroll
      for (int q = 0; q < 4; ++q) acc[i][j][q] = 0.f;

  int nkp[3];
  nkp[0] = k0 / BKT;
  nkp[1] = A1 ? k1 / BKT : 0;
  nkp[2] = A2 ? k2 / BKT : 0;
  const int total = nkp[0] + nkp[1] + nkp[2];

  float4 aR[4], wR[4];
  // staging chunk: q = tid + 256*i ; tile row r = q>>3 ; float4-col f = q&7
  auto pf = [&](int pp, int kt) {
    const float* Ap; const float* Wp; int ldw;
    if (pp == 0)      { Ap = A0; Wp = W0; ldw = ldw0; }
    else if (pp == 1) { Ap = A1; Wp = W1; ldw = ldw1; }
    else              { Ap = A2; Wp = W2; ldw = ldw2; }
    #pragma unroll
    for (int i = 0; i < 4; ++i) {
      const int q = tid + 256 * i, r = q >> 3, f = q & 7;
      aR[i] = *(const float4*)(Ap + (size_t)(row0 + r) * HD + kt * BKT + f * 4);
      wR[i] = *(const float4*)(Wp + (size_t)(col0 + r) * ldw + kt * BKT + f * 4);
    }
  };

  int p = 0, kt = 0;
  pf(0, 0);
  for (int s = 0; s < total; ++s) {
    __syncthreads();  // previous tile's compute finished
    #pragma unroll
    for (int i = 0; i < 4; ++i) {
      const int q = tid + 256 * i, r = q >> 3, f = q & 7;
      *(ushort4*)&As[r * LDP + f * 4] =
          make_ushort4(f2b(aR[i].x), f2b(aR[i].y), f2b(aR[i].z), f2b(aR[i].w));
      *(ushort4*)&Bs[r * LDP + f * 4] =
          make_ushort4(f2b(wR[i].x), f2b(wR[i].y), f2b(wR[i].z), f2b(wR[i].w));
    }
    __syncthreads();  // tile visible
    int np = p, nkt = kt + 1;
    if (nkt == nkp[np]) { ++np; nkt = 0; }
    if (s + 1 < total) pf(np, nkt);  // global latency hides under MFMAs below

    bf16x8 af[4], bg_[4];
    #pragma unroll
    for (int fm = 0; fm < 4; ++fm)
      af[fm] = *(const bf16x8*)&As[(wr * 64 + fm * 16 + fr) * LDP + fq * 8];
    #pragma unroll
    for (int fn = 0; fn < 4; ++fn)
      bg_[fn] = *(const bf16x8*)&Bs[(wc * 64 + fn * 16 + fr) * LDP + fq * 8];
    #pragma unroll
    for (int fm = 0; fm < 4; ++fm)
      #pragma unroll
      for (int fn = 0; fn < 4; ++fn)
        acc[fm][fn] = __builtin_amdgcn_mfma_f32_16x16x32_bf16(
            af[fm], bg_[fn], acc[fm][fn], 0, 0, 0);
    p = np; kt = nkt;
  }

  // epilogue: D row = fq*4+j, col = fr (within 16x16 fragment)
  #pragma unroll
  for (int fm = 0; fm < 4; ++fm) {
    #pragma unroll
    for (int fn = 0; fn < 4; ++fn) {
      const int c = col0 + wc * 64 + fn * 16 + fr;
      #pragma unroll
      for (int j = 0; j < 4; ++j) {
        const int m = row0 + wr * 64 + fm * 16 + fq * 4 + j;
        float a = acc[fm][fn][j];
        if (bias) a += bias[c];
        if (mode == 1) {
          a = fmaxf(a, 0.f);
        } else if (mode == 2) {
          a = sigmoidf_(a);
        } else if (mode == 3) {
          a = prev[(size_t)m * HD + c] * sigmoidf_(a);
        } else if (mode == 4) {
          float nv = fmaxf(a, 0.f);
          float zz = zbuf[(size_t)m * HD + c];
          float pv = prev[(size_t)m * HD + c];
          a = (1.f - zz) * nv + zz * pv;
        }
        out[(size_t)m * HD + c] = a;
      }
    }
  }
}

// ---------------------------------------------------------------------------
// K2: attention, one node per block, spat held in registers (read once).
// ---------------------------------------------------------------------------
__global__ __launch_bounds__(256) void k_attn(const float* __restrict__ spat,
                                              const float* __restrict__ v,
                                              float* __restrict__ hagg) {
  __shared__ float attn_s[NE];
  __shared__ float4 part_s[4][64];
  const int n = blockIdx.x;
  const int t = threadIdx.x;
  const int w = t >> 6, fb = t & 63;
  const float4* sp = (const float4*)(spat + (size_t)n * NE * HD);
  const float4 v4 = ((const float4*)(v + (size_t)n * HD))[fb];

  float4 sreg[8];
  float part[8];
  #pragma unroll
  for (int i = 0; i < 8; ++i) {
    sreg[i] = sp[t + 256 * i];
    part[i] = sreg[i].x * v4.x + sreg[i].y * v4.y + sreg[i].z * v4.z + sreg[i].w * v4.w;
  }
  #pragma unroll
  for (int i = 0; i < 8; ++i) {
    float p = part[i];
    #pragma unroll
    for (int m = 1; m < 64; m <<= 1) p += __shfl_xor(p, m, 64);
    if (fb == 0) attn_s[w + 4 * i] = p;
  }
  __syncthreads();
  float mx = -1e30f;
  for (int e = 0; e < NE; ++e) mx = fmaxf(mx, attn_s[e] * 4.0f);
  float s = 0.f;
  for (int e = 0; e < NE; ++e) s += __expf(attn_s[e] * 4.0f - mx);
  const float inv = 1.f / s;
  float4 hp = make_float4(0.f, 0.f, 0.f, 0.f);
  #pragma unroll
  for (int i = 0; i < 8; ++i) {
    const float wgt = __expf(attn_s[w + 4 * i] * 4.0f - mx) * inv;
    hp.x += wgt * sreg[i].x;
    hp.y += wgt * sreg[i].y;
    hp.z += wgt * sreg[i].z;
    hp.w += wgt * sreg[i].w;
  }
  part_s[w][fb] = hp;
  __syncthreads();
  if (t < 64) {
    float4 s0 = part_s[0][t], s1 = part_s[1][t], s2 = part_s[2][t], s3 = part_s[3][t];
    float4 o = make_float4(s0.x + s1.x + s2.x + s3.x, s0.y + s1.y + s2.y + s3.y,
                           s0.z + s1.z + s2.z + s3.z, s0.w + s1.w + s2.w + s3.w);
    ((float4*)(hagg + (size_t)n * HD))[t] = o;
  }
}

// ---------------------------------------------------------------------------
__global__ __launch_bounds__(256) void k_xe(const float* __restrict__ xy,
                                            const float* __restrict__ Wxy,
                                            float* __restrict__ xe) {
  const int h = threadIdx.x;
  const float w0 = Wxy[2 * h], w1 = Wxy[2 * h + 1];
  for (int n = blockIdx.x; n < NND; n += gridDim.x) {
    const float x0 = xy[2 * n], x1 = xy[2 * n + 1];
    xe[(size_t)n * HD + h] = fmaxf(x0 * w0 + x1 * w1, 0.f);
  }
}

// ---------------------------------------------------------------------------
__global__ __launch_bounds__(256) void k_pred(const float* __restrict__ hid,
                                              const float* __restrict__ Wp,
                                              const float* __restrict__ bp,
                                              float* __restrict__ out) {
  const int t = threadIdx.x;
  const int w = t >> 6, lane = t & 63;
  const int n = blockIdx.x * 4 + w;
  const float* h = hid + (size_t)n * HD;
  const float h0 = h[lane], h1 = h[lane + 64], h2 = h[lane + 128], h3 = h[lane + 192];
  #pragma unroll
  for (int oc = 0; oc < ODIM; ++oc) {
    const float* wr = Wp + oc * HD;
    float p = h0 * wr[lane] + h1 * wr[lane + 64] + h2 * wr[lane + 128] + h3 * wr[lane + 192];
    #pragma unroll
    for (int m = 1; m < 64; m <<= 1) p += __shfl_xor(p, m, 64);
    if (lane == 0) out[n * ODIM + oc] = p + bp[oc];
  }
}

// ---------------------------------------------------------------------------
extern "C" void kernel_launch(void* const* d_in, const int* in_sizes, int n_in,
                              void* d_out, int out_size, void* d_ws, size_t ws_size,
                              hipStream_t stream) {
  const float* xy   = (const float*)d_in[0];
  const float* th   = (const float*)d_in[1];
  const float* spat = (const float*)d_in[2];
  const float* prev = (const float*)d_in[3];
  const float* Wt   = (const float*)d_in[4];
  const float* bt   = (const float*)d_in[5];
  const float* Ws   = (const float*)d_in[6];
  // d_in[7] = bs: constant across edges -> cancels in softmax, unused
  const float* Wxy  = (const float*)d_in[8];
  const float* Whe  = (const float*)d_in[9];
  const float* Wih  = (const float*)d_in[10];
  const float* Whh  = (const float*)d_in[11];
  const float* bg   = (const float*)d_in[12];
  const float* Wp   = (const float*)d_in[13];
  const float* bp   = (const float*)d_in[14];
  float* out = (float*)d_out;

  float* ws   = (float*)d_ws;
  float* MT   = ws;                                // 256*256
  float* u    = MT + 65536;                        // 256
  float* vbuf = u + 256;                           // N*256 (aliased: z after attn)
  float* hagg = vbuf + (size_t)NND * HD;           // N*256 (aliased: rp after H_e)
  float* xe   = hagg + (size_t)NND * HD;           // N*256
  float* He   = xe + (size_t)NND * HD;             // N*256

  const dim3 gg(HD / BN, NND / BM);  // (2, 128)

  k_mt<<<256, 256, 0, stream>>>(Wt, bt, Ws, MT, u);
  // v = th @ MT^T + u
  gemm_bf16<<<gg, 256, 0, stream>>>(th, MT, HD, HD,
                                    nullptr, nullptr, 0, 0,
                                    nullptr, nullptr, 0, 0,
                                    u, nullptr, nullptr, vbuf, 0);
  k_attn<<<NND, 256, 0, stream>>>(spat, vbuf, hagg);
  k_xe<<<2048, 256, 0, stream>>>(xy, Wxy, xe);
  // H_e = relu([th, Hagg] @ W_he^T)
  gemm_bf16<<<gg, 256, 0, stream>>>(th, Whe, 2 * HD, HD,
                                    hagg, Whe + HD, 2 * HD, HD,
                                    nullptr, nullptr, 0, 0,
                                    nullptr, nullptr, nullptr, He, 1);
  // z = sigmoid(cat@Wih0^T + prev@Whh0^T + b0)    (z overwrites vbuf)
  gemm_bf16<<<gg, 256, 0, stream>>>(xe, Wih, 2 * HD, HD,
                                    He, Wih + HD, 2 * HD, HD,
                                    prev, Whh, HD, HD,
                                    bg, nullptr, nullptr, vbuf, 2);
  // rp = prev * sigmoid(cat@Wih1^T + prev@Whh1^T + b1)   (rp overwrites hagg)
  gemm_bf16<<<gg, 256, 0, stream>>>(xe, Wih + 131072, 2 * HD, HD,
                                    He, Wih + 131072 + HD, 2 * HD, HD,
                                    prev, Whh + 65536, HD, HD,
                                    bg + HD, prev, nullptr, hagg, 3);
  // hidden = (1-z)*relu(cat@Wih2^T + rp@Whh2^T + b2) + z*prev
  gemm_bf16<<<gg, 256, 0, stream>>>(xe, Wih + 262144, 2 * HD, HD,
                                    He, Wih + 262144 + HD, 2 * HD, HD,
                                    hagg, Whh + 131072, HD, HD,
                                    bg + 2 * HD, prev, vbuf, out + NND * ODIM, 4);
  k_pred<<<NND / 4, 256, 0, stream>>>(out + NND * ODIM, Wp, bp, out);
}